// Round 5
// baseline (211.967 us; speedup 1.0000x reference)
//
#include <hip/hip_runtime.h>
#include <math.h>

#define NN 4096
#define HH 4
#define JT 32   // j per tile
#define NT 64   // tiles per block (2048/32)

typedef _Float16 h4 __attribute__((ext_vector_type(4)));
typedef float f4 __attribute__((ext_vector_type(4)));

// ---------------- K1: htT16[h][d][j] = fp16((h@W)[j][h*128+d]) ----------------
__global__ __launch_bounds__(512) void k_htgemm(const float* __restrict__ h,
                                                const float* __restrict__ W,
                                                _Float16* __restrict__ htT) {
  __shared__ float hs[16][128];
  const int i0 = blockIdx.x * 16;
  for (int idx = threadIdx.x; idx < 16 * 128; idx += 512)
    hs[idx >> 7][idx & 127] = h[(i0 + (idx >> 7)) * 128 + (idx & 127)];
  __syncthreads();
  const int c = threadIdx.x;  // output column 0..511
  float acc[16];
#pragma unroll
  for (int r = 0; r < 16; ++r) acc[r] = 0.f;
  for (int k = 0; k < 128; ++k) {
    const float w = W[k * 512 + c];
#pragma unroll
    for (int r = 0; r < 16; ++r) acc[r] = fmaf(hs[r][k], w, acc[r]);
  }
  const int hc = c >> 7, d = c & 127;
  _Float16* dst = htT + (size_t)(hc * 128 + d) * NN + i0;
#pragma unroll
  for (int g = 0; g < 4; ++g) {
    h4 v;
    v.x = (_Float16)acc[g * 4 + 0];
    v.y = (_Float16)acc[g * 4 + 1];
    v.z = (_Float16)acc[g * 4 + 2];
    v.w = (_Float16)acc[g * 4 + 3];
    *(h4*)(dst + g * 4) = v;
  }
}

// ---------------- K2: src/tgt from htT16 ----------------
__global__ __launch_bounds__(256) void k_srctgt(const _Float16* __restrict__ htT,
                                                const float* __restrict__ a,
                                                float* __restrict__ src,
                                                float* __restrict__ tgt) {
  const int b = blockIdx.x;      // 64 blocks: h = b>>4, chunk = b&15
  const int hh = b >> 4;
  const int i = (b & 15) * 256 + threadIdx.x;
  const _Float16* base = htT + (size_t)hh * 128 * NN + i;
  float s = 0.f, t = 0.f;
#pragma unroll 8
  for (int d = 0; d < 128; ++d) {
    const float v = (float)base[(size_t)d * NN];
    s = fmaf(v, a[hh * 256 + d], s);
    t = fmaf(v, a[hh * 256 + 128 + d], t);
  }
  src[hh * NN + i] = s;
  tgt[hh * NN + i] = t;
}

// ---------------- K3: fused attention ----------------
// LDS (bytes):
//   [0, 65536)       Vs[2][512 rows][64 B]  fp16, 8B-chunk XOR(row&7) swizzle
//   [65536, 69888)   dist[2][32 j][17 i] f32
//   [69888, 71040)   tgts[2][4][36] f32
//   [71040, 73600)   ps[2][16][40] fp16 (rows 0..2 = xyz, 3 = 1, 4..15 = 0)
#define VSBUF 32768
#define DIST_OFF 65536
#define TGTS_OFF 69888
#define PS_OFF 71040
#define SMEM_BYTES 73600

__global__ __launch_bounds__(512, 4) void k_attn(
    const _Float16* __restrict__ htT, const int* __restrict__ adj,
    const float* __restrict__ pos, const float* __restrict__ src,
    const float* __restrict__ tgt, float* __restrict__ hp_part,
    float* __restrict__ ppart) {
  __shared__ __attribute__((aligned(16))) unsigned char smem[SMEM_BYTES];
  float* dist_s = (float*)(smem + DIST_OFF);   // buf stride 544 floats
  float* tgts   = (float*)(smem + TGTS_OFF);   // buf stride 144 floats

  const int tid = threadIdx.x;
  const int ib = (int)blockIdx.x >> 1, jh = (int)blockIdx.x & 1;
  const int i0 = ib * 16, jbase = jh * 2048;

  const int w = tid >> 6, lane = tid & 63;
  const int hh = w & 3, kp = w >> 2;   // head, k-half
  const int il = lane & 15, kg = lane >> 4;

  const float srcv = src[hh * NN + i0 + il];

  // ---- staging role constants ----
  const int sj = tid & 31;   // j within tile
  const int si = tid >> 5;   // i row
  const float pix = pos[(i0 + si) * 3], piy = pos[(i0 + si) * 3 + 1],
              piz = pos[(i0 + si) * 3 + 2];
  const int* adjp = adj + (size_t)(i0 + si) * NN + jbase + sj;
  const float* posj = pos + (size_t)(jbase + sj) * 3;
  const _Float16* vsrc = htT + (size_t)tid * NN + jbase;  // V row = tid
  unsigned char* vwr = smem + tid * 64;
  const int vsw = (tid >> 1) & 3;  // 16B-slot xor
  const int vhs = tid & 1;         // half swap
  const int th = tid >> 5;         // tgts role head (tid<128)
  const int prow = (tid - 128) >> 5;  // ps role row (128<=tid<256)

  // ---- compute-role read offsets ----
  const int vrd_row = hh * 128 + il;                      // + dt*16
  const int vrd_chunk = (((kp * 4 + kg) ^ (il & 7)) << 3);
  const int ps_rd = il * 80 + kp * 32 + kg * 8;           // bytes within ps buf

  f4 acc[8];
#pragma unroll
  for (int dt = 0; dt < 8; ++dt) acc[dt] = (f4){0.f, 0.f, 0.f, 0.f};
  f4 pacc = (f4){0.f, 0.f, 0.f, 0.f};

  float4 v[4];
  int av;
  float qx, qy, qz, ex;

#define LOADT(t)                                                      \
  {                                                                   \
    _Pragma("unroll") for (int q = 0; q < 4; ++q)                     \
        v[q] = *(const float4*)(vsrc + (t) * 32 + q * 8);             \
    av = adjp[(t) * 32];                                              \
    qx = posj[(t) * 96 + 0];                                          \
    qy = posj[(t) * 96 + 1];                                          \
    qz = posj[(t) * 96 + 2];                                          \
    ex = 0.f;                                                         \
    if (tid < 128) ex = tgt[th * NN + jbase + (t) * 32 + sj];         \
    else if (tid < 256) ex = prow < 3 ? posj[(t) * 96 + prow] : 1.f;  \
  }

#define WRITET(b)                                                       \
  {                                                                     \
    _Pragma("unroll") for (int q = 0; q < 4; ++q) {                     \
      float4 wv = v[q];                                                 \
      if (vhs) wv = (float4){wv.z, wv.w, wv.x, wv.y};                   \
      *(float4*)(vwr + (b) * VSBUF + ((q ^ vsw) << 4)) = wv;            \
    }                                                                   \
    const float dx = pix - qx, dy = piy - qy, dz = piz - qz;            \
    const float dist = sqrtf(dx * dx + dy * dy + dz * dz);              \
    dist_s[(b) * 544 + sj * 17 + si] = av > 0 ? dist : 1e30f;           \
    if (tid < 128) tgts[(b) * 144 + th * 36 + sj] = ex;                 \
    else if (tid < 256)                                                 \
      ((_Float16*)(smem + PS_OFF))[(b) * 640 + prow * 40 + sj] =        \
          (_Float16)ex;                                                 \
  }

  // ---- prologue: zero ps rows 4..15 (both bufs), stage tile 0 ----
  for (int idx = tid; idx < 960; idx += 512) {
    const int b = idx / 480, r = idx % 480;
    ((_Float16*)(smem + PS_OFF))[b * 640 + 160 + r] = (_Float16)0.f;
  }
  LOADT(0);
  WRITET(0);
  __syncthreads();

  for (int t = 0; t < NT; ++t) {
    const int cur = t & 1;
    if (t < NT - 1) LOADT(t + 1);
    // ---- compute tile t ----
    {
      const float* dcur = dist_s + cur * 544;
      const int jf = kp * 16 + kg * 4;
      const float4 tt = *(const float4*)(tgts + cur * 144 + hh * 36 + jf);
      const float d0 = dcur[(jf + 0) * 17 + il];
      const float d1 = dcur[(jf + 1) * 17 + il];
      const float d2 = dcur[(jf + 2) * 17 + il];
      const float d3 = dcur[(jf + 3) * 17 + il];
      float e0 = srcv + tt.x - d0; e0 = fmaxf(e0, 0.2f * e0);
      float e1 = srcv + tt.y - d1; e1 = fmaxf(e1, 0.2f * e1);
      float e2 = srcv + tt.z - d2; e2 = fmaxf(e2, 0.2f * e2);
      float e3 = srcv + tt.w - d3; e3 = fmaxf(e3, 0.2f * e3);
      h4 af;
      af.x = (_Float16)__expf(e0);
      af.y = (_Float16)__expf(e1);
      af.z = (_Float16)__expf(e2);
      af.w = (_Float16)__expf(e3);
#pragma unroll
      for (int dt = 0; dt < 8; ++dt) {
        const h4 bv = *(const h4*)(smem + cur * VSBUF +
                                   (vrd_row + dt * 16) * 64 + vrd_chunk);
        acc[dt] = __builtin_amdgcn_mfma_f32_16x16x16f16(af, bv, acc[dt], 0, 0, 0);
      }
      const h4 pv = *(const h4*)(smem + PS_OFF + cur * 1280 + ps_rd);
      pacc = __builtin_amdgcn_mfma_f32_16x16x16f16(af, pv, pacc, 0, 0, 0);
    }
    if (t < NT - 1) WRITET(cur ^ 1);
    __syncthreads();
  }
#undef LOADT
#undef WRITET

  // ---- epilogue: sum k-halves via LDS, write partials ----
  float* accs = (float*)smem;                    // [4][16][128] = 32 KB
  float* paccs = (float*)(smem + 32768);         // [8][16][4] = 2 KB
  if (kp == 1) {
#pragma unroll
    for (int dt = 0; dt < 8; ++dt)
#pragma unroll
      for (int r = 0; r < 4; ++r)
        accs[(hh * 16 + kg * 4 + r) * 128 + dt * 16 + il] = acc[dt][r];
  }
  if (il < 4) {
#pragma unroll
    for (int r = 0; r < 4; ++r)
      paccs[((hh * 2 + kp) * 16 + kg * 4 + r) * 4 + il] = pacc[r];
  }
  __syncthreads();
  if (kp == 0) {
    float* hpb = hp_part + ((size_t)(jh * 4 + hh) * NN + i0) * 128;
#pragma unroll
    for (int dt = 0; dt < 8; ++dt)
#pragma unroll
      for (int r = 0; r < 4; ++r)
        hpb[(kg * 4 + r) * 128 + dt * 16 + il] =
            acc[dt][r] + accs[(hh * 16 + kg * 4 + r) * 128 + dt * 16 + il];
  }
  if (tid < 256) {
    const int c = tid & 3, i2 = (tid >> 2) & 15, h2 = tid >> 6;
    ppart[((size_t)(jh * 4 + h2) * NN + i0 + i2) * 4 + c] =
        paccs[(h2 * 2 * 16 + i2) * 4 + c] +
        paccs[((h2 * 2 + 1) * 16 + i2) * 4 + c];
  }
}

// ---------------- K5: normalize + head-mean + LayerNorm + residual + pos ----------------
__global__ __launch_bounds__(128) void k_finish(
    const float* __restrict__ hp_part, const float* __restrict__ ppart,
    const float* __restrict__ hin, const float* __restrict__ pos,
    const float* __restrict__ gamma, const float* __restrict__ beta,
    float* __restrict__ hout, float* __restrict__ out_pos) {
  __shared__ float red[2][2];
  const int i = blockIdx.x, d = threadIdx.x;
  float Li[4];
  float v = 0.f;
#pragma unroll
  for (int hx = 0; hx < 4; ++hx) {
    Li[hx] = 1.f / (ppart[((size_t)hx * NN + i) * 4 + 3] +
                    ppart[((size_t)(4 + hx) * NN + i) * 4 + 3]);
    v += (hp_part[((size_t)hx * NN + i) * 128 + d] +
          hp_part[((size_t)(4 + hx) * NN + i) * 128 + d]) * Li[hx];
  }
  v *= 0.25f;
  float s = v, sq = v * v;
#pragma unroll
  for (int off = 32; off >= 1; off >>= 1) {
    s += __shfl_xor(s, off, 64);
    sq += __shfl_xor(sq, off, 64);
  }
  const int wv = d >> 6;
  if ((d & 63) == 0) { red[wv][0] = s; red[wv][1] = sq; }
  __syncthreads();
  s = red[0][0] + red[1][0];
  sq = red[0][1] + red[1][1];
  const float mu = s * (1.f / 128.f);
  const float var = sq * (1.f / 128.f) - mu * mu;
  const float hn = (v - mu) * rsqrtf(var + 1e-5f) * gamma[d] + beta[d];
  hout[i * 128 + d] = hin[i * 128 + d] + hn;
  if (d < 3) {
    float sp = 0.f;
#pragma unroll
    for (int hx = 0; hx < 4; ++hx)
      sp += (ppart[((size_t)hx * NN + i) * 4 + d] +
             ppart[((size_t)(4 + hx) * NN + i) * 4 + d]) * Li[hx];
    out_pos[i * 3 + d] = 2.f * pos[i * 3 + d] - 0.25f * sp;
  }
}

extern "C" void kernel_launch(void* const* d_in, const int* in_sizes, int n_in,
                              void* d_out, int out_size, void* d_ws, size_t ws_size,
                              hipStream_t stream) {
  const float* h     = (const float*)d_in[0];
  const int*   adj   = (const int*)d_in[1];
  const float* pos   = (const float*)d_in[2];
  const float* W     = (const float*)d_in[3];
  const float* a     = (const float*)d_in[4];
  const float* gamma = (const float*)d_in[5];
  const float* beta  = (const float*)d_in[6];
  float* out = (float*)d_out;

  _Float16* htT = (_Float16*)d_ws;             // 4*128*4096 halves = 4 MB
  float* fws = (float*)(htT + 4 * 128 * NN);
  float* src = fws;                            // 4*N
  float* tgt = src + HH * NN;                  // 4*N
  float* hp_part = tgt + HH * NN;              // 2*4*N*128 = 16 MB
  float* ppart = hp_part + 8 * NN * 128;       // 2*4*N*4 = 512 KB

  k_htgemm<<<NN / 16, 512, 0, stream>>>(h, W, htT);
  k_srctgt<<<64, 256, 0, stream>>>(htT, a, src, tgt);
  k_attn<<<512, 512, 0, stream>>>(htT, adj, pos, src, tgt, hp_part, ppart);
  k_finish<<<NN, 128, 0, stream>>>(hp_part, ppart, h, pos, gamma, beta, out,
                                   out + NN * 128);
}

// Round 6
// 88.327 us; speedup vs baseline: 2.3998x; 2.3998x over previous
//
#include <hip/hip_runtime.h>
#include <hip/hip_bf16.h>
#include <math.h>

#define NN 4096
#define HH 4

typedef _Float16 h2 __attribute__((ext_vector_type(2)));
typedef _Float16 h4 __attribute__((ext_vector_type(4)));
typedef _Float16 h8 __attribute__((ext_vector_type(8)));
typedef float f4 __attribute__((ext_vector_type(4)));

// ---------------- K1: ht GEMM -> vfrag + posfrag + src/tgt ----------------
// vfrag element (h, jt, lane, dt, e) = ht[j = jt*16 + (lane>>4)*4+e][h*128 + dt*16 + (lane&15)]
// addr (halves) = ((h*256 + jt)*64 + lane)*32 + dt*4 + e
__global__ __launch_bounds__(512) void k_htgemm(const float* __restrict__ h,
                                                const float* __restrict__ W,
                                                const float* __restrict__ a,
                                                const float* __restrict__ pos,
                                                _Float16* __restrict__ vfrag,
                                                _Float16* __restrict__ posfrag,
                                                float* __restrict__ src,
                                                float* __restrict__ tgt) {
  __shared__ float hs[16][128];
  __shared__ float red[8][16][2];
  const int jt = blockIdx.x;      // 16-node tile
  const int i0 = jt * 16;
  const int tid = threadIdx.x;
  for (int idx = tid; idx < 16 * 128; idx += 512)
    hs[idx >> 7][idx & 127] = h[(i0 + (idx >> 7)) * 128 + (idx & 127)];
  __syncthreads();
  const int c = tid;  // output column 0..511
  float acc[16];
#pragma unroll
  for (int r = 0; r < 16; ++r) acc[r] = 0.f;
  for (int k = 0; k < 128; ++k) {
    const float w = W[k * 512 + c];
#pragma unroll
    for (int r = 0; r < 16; ++r) acc[r] = fmaf(hs[r][k], w, acc[r]);
  }
  const int hc = c >> 7, d = c & 127;
  // vfrag stores
  _Float16* vb = vfrag + ((size_t)(hc * 256 + jt) * 64) * 32 + (d >> 4) * 4;
#pragma unroll
  for (int rg = 0; rg < 4; ++rg) {
    h4 v;
    v.x = (_Float16)acc[rg * 4 + 0];
    v.y = (_Float16)acc[rg * 4 + 1];
    v.z = (_Float16)acc[rg * 4 + 2];
    v.w = (_Float16)acc[rg * 4 + 3];
    *(h4*)(vb + ((d & 15) + 16 * rg) * 32) = v;
  }
  // src/tgt: butterfly reduce over d (each wave = (h, d-half))
  const float av = a[hc * 256 + d];
  const float bvv = a[hc * 256 + 128 + d];
  float sv[16], tv[16];
#pragma unroll
  for (int r = 0; r < 16; ++r) { sv[r] = acc[r] * av; tv[r] = acc[r] * bvv; }
#pragma unroll
  for (int off = 32; off >= 1; off >>= 1) {
#pragma unroll
    for (int r = 0; r < 16; ++r) {
      sv[r] += __shfl_xor(sv[r], off, 64);
      tv[r] += __shfl_xor(tv[r], off, 64);
    }
  }
  const int w = tid >> 6;
  if ((tid & 63) == 0) {
#pragma unroll
    for (int r = 0; r < 16; ++r) { red[w][r][0] = sv[r]; red[w][r][1] = tv[r]; }
  }
  // posfrag (tid < 64)
  if (tid < 64) {
    const int rg = tid >> 4, n = tid & 15;
    h4 pv;
#pragma unroll
    for (int e = 0; e < 4; ++e) {
      const int j = i0 + rg * 4 + e;
      pv[e] = (_Float16)(n < 3 ? pos[j * 3 + n] : (n == 3 ? 1.f : 0.f));
    }
    *(h4*)(posfrag + (size_t)(jt * 64 + tid) * 4) = pv;
  }
  __syncthreads();
  if (tid < 128) {
    const int h2_ = tid >> 5, k = tid & 31, r = k >> 1, st = k & 1;
    const float vsum = red[h2_ * 2][r][st] + red[h2_ * 2 + 1][r][st];
    (st ? tgt : src)[h2_ * NN + i0 + r] = vsum;
  }
}

// ---------------- K2: barrier-free fused attention ----------------
// block: 512 thr = 8 waves = 4 heads x 2 j-interleave; i-tile 32, j-range 1024.
// LDS: dist16 [32][1032] fp16 (masked dist), then reused as f32 epilogue buffers.
#define JROW 1032
#define EPS_OFF 0
#define PACC_OFF 65536
#define SMEM_BYTES 67584

__global__ __launch_bounds__(512, 4) void k_attn(
    const _Float16* __restrict__ vfrag, const _Float16* __restrict__ posfrag,
    const int* __restrict__ adj, const float* __restrict__ pos,
    const float* __restrict__ src, const float* __restrict__ tgt,
    __hip_bfloat16* __restrict__ hp_part, __hip_bfloat16* __restrict__ ppart) {
  __shared__ __attribute__((aligned(16))) unsigned char smem[SMEM_BYTES];
  _Float16* dist16 = (_Float16*)smem;

  const int tid = threadIdx.x;
  const int ib = (int)blockIdx.x >> 2, jhb = (int)blockIdx.x & 3;
  const int i0 = ib * 32;
  const int jb = jhb * 1024;

  // ================= fill phase: masked dist (fp16) =================
  {
    const int jl = tid & 63, ig = tid >> 6;
    float pix[4], piy[4], piz[4];
#pragma unroll
    for (int q = 0; q < 4; ++q) {
      const int i = ig * 4 + q;
      pix[q] = pos[(i0 + i) * 3 + 0];
      piy[q] = pos[(i0 + i) * 3 + 1];
      piz[q] = pos[(i0 + i) * 3 + 2];
    }
    for (int cc = 0; cc < 8; ++cc) {
      const int jloc = cc * 128 + jl * 2;
      const int j = jb + jloc;
      const float qx0 = pos[j * 3 + 0], qy0 = pos[j * 3 + 1], qz0 = pos[j * 3 + 2];
      const float qx1 = pos[j * 3 + 3], qy1 = pos[j * 3 + 4], qz1 = pos[j * 3 + 5];
#pragma unroll
      for (int q = 0; q < 4; ++q) {
        const int i = ig * 4 + q;
        const int2 av = *(const int2*)(adj + (size_t)(i0 + i) * NN + j);
        float dx = pix[q] - qx0, dy = piy[q] - qy0, dz = piz[q] - qz0;
        const float d0 = sqrtf(dx * dx + dy * dy + dz * dz);
        dx = pix[q] - qx1; dy = piy[q] - qy1; dz = piz[q] - qz1;
        const float d1 = sqrtf(dx * dx + dy * dy + dz * dz);
        h2 dd;
        dd.x = (_Float16)(av.x > 0 ? d0 : 3e4f);
        dd.y = (_Float16)(av.y > 0 ? d1 : 3e4f);
        *(h2*)(dist16 + i * JROW + jloc) = dd;
      }
    }
  }
  __syncthreads();

  // ================= main loop: barrier-free =================
  const int w = tid >> 6, lane = tid & 63;
  const int hh = w & 3, kp = w >> 2;
  const int il = lane & 15, kg = lane >> 4;

  float srcv[2];
  srcv[0] = src[hh * NN + i0 + il];
  srcv[1] = src[hh * NN + i0 + 16 + il];

  f4 acc[2][8];
#pragma unroll
  for (int mp = 0; mp < 2; ++mp)
#pragma unroll
    for (int dt = 0; dt < 8; ++dt) acc[mp][dt] = (f4){0.f, 0.f, 0.f, 0.f};
  f4 pacc[2];
  pacc[0] = (f4){0.f, 0.f, 0.f, 0.f};
  pacc[1] = (f4){0.f, 0.f, 0.f, 0.f};

  const int jt0 = (jb >> 4) + kp;  // global 16-tiles: jt0 + 2t
  const _Float16* vbase = vfrag + ((size_t)(hh * 256) * 64 + lane) * 32;
  const _Float16* pbase = posfrag + (size_t)lane * 4;
  const float* tbase = tgt + hh * NN + jb + kp * 16 + kg * 4;

#pragma unroll 2
  for (int t = 0; t < 32; ++t) {
    const int jt = jt0 + 2 * t;
    const int toff = (2 * t + kp) * 16;
    // B fragments (coalesced 16B loads, L2-resident)
    const _Float16* vf = vbase + (size_t)jt * 64 * 32;
    const h8 v01 = *(const h8*)(vf);
    const h8 v23 = *(const h8*)(vf + 8);
    const h8 v45 = *(const h8*)(vf + 16);
    const h8 v67 = *(const h8*)(vf + 24);
    h4 vfj[8];
    vfj[0] = __builtin_shufflevector(v01, v01, 0, 1, 2, 3);
    vfj[1] = __builtin_shufflevector(v01, v01, 4, 5, 6, 7);
    vfj[2] = __builtin_shufflevector(v23, v23, 0, 1, 2, 3);
    vfj[3] = __builtin_shufflevector(v23, v23, 4, 5, 6, 7);
    vfj[4] = __builtin_shufflevector(v45, v45, 0, 1, 2, 3);
    vfj[5] = __builtin_shufflevector(v45, v45, 4, 5, 6, 7);
    vfj[6] = __builtin_shufflevector(v67, v67, 0, 1, 2, 3);
    vfj[7] = __builtin_shufflevector(v67, v67, 4, 5, 6, 7);
    const h4 pf = *(const h4*)(pbase + (size_t)jt * 256);
    const float4 tt = *(const float4*)(tbase + 2 * t * 16);
#pragma unroll
    for (int mp = 0; mp < 2; ++mp) {
      const h4 dd = *(const h4*)(dist16 + (mp * 16 + il) * JROW + toff + kg * 4);
      float e0 = (srcv[mp] + tt.x) - (float)dd.x;
      float e1 = (srcv[mp] + tt.y) - (float)dd.y;
      float e2 = (srcv[mp] + tt.z) - (float)dd.z;
      float e3 = (srcv[mp] + tt.w) - (float)dd.w;
      e0 = fmaxf(e0, 0.2f * e0);
      e1 = fmaxf(e1, 0.2f * e1);
      e2 = fmaxf(e2, 0.2f * e2);
      e3 = fmaxf(e3, 0.2f * e3);
      h4 af;
      af.x = (_Float16)__expf(e0);
      af.y = (_Float16)__expf(e1);
      af.z = (_Float16)__expf(e2);
      af.w = (_Float16)__expf(e3);
#pragma unroll
      for (int dt = 0; dt < 8; ++dt)
        acc[mp][dt] = __builtin_amdgcn_mfma_f32_16x16x16f16(af, vfj[dt], acc[mp][dt], 0, 0, 0);
      pacc[mp] = __builtin_amdgcn_mfma_f32_16x16x16f16(af, pf, pacc[mp], 0, 0, 0);
    }
  }

  // ================= epilogue: sum kp halves, write bf16 partials =================
  __syncthreads();
  float* eps = (float*)(smem + EPS_OFF);      // [4 h][32 i][128 d]
  float* pacc_s = (float*)(smem + PACC_OFF);  // [4 h][32 i][4]
  if (kp == 1) {
#pragma unroll
    for (int mp = 0; mp < 2; ++mp)
#pragma unroll
      for (int dt = 0; dt < 8; ++dt)
#pragma unroll
        for (int r = 0; r < 4; ++r)
          eps[(hh * 32 + mp * 16 + kg * 4 + r) * 128 + dt * 16 + il] = acc[mp][dt][r];
    if (il < 4) {
#pragma unroll
      for (int mp = 0; mp < 2; ++mp)
#pragma unroll
        for (int r = 0; r < 4; ++r)
          pacc_s[(hh * 32 + mp * 16 + kg * 4 + r) * 4 + il] = pacc[mp][r];
    }
  }
  __syncthreads();
  if (kp == 0) {
    __hip_bfloat16* hpb =
        hp_part + ((size_t)(jhb * 4 + hh) * NN + i0) * 128;
#pragma unroll
    for (int mp = 0; mp < 2; ++mp)
#pragma unroll
      for (int dt = 0; dt < 8; ++dt)
#pragma unroll
        for (int r = 0; r < 4; ++r) {
          const int ii = mp * 16 + kg * 4 + r;
          const float s = acc[mp][dt][r] + eps[(hh * 32 + ii) * 128 + dt * 16 + il];
          hpb[(size_t)ii * 128 + dt * 16 + il] = __float2bfloat16(s);
        }
    if (il < 4) {
#pragma unroll
      for (int mp = 0; mp < 2; ++mp)
#pragma unroll
        for (int r = 0; r < 4; ++r) {
          const int ii = mp * 16 + kg * 4 + r;
          const float s = pacc[mp][r] + pacc_s[(hh * 32 + ii) * 4 + il];
          ppart[((size_t)(jhb * 4 + hh) * NN + i0 + ii) * 4 + il] = __float2bfloat16(s);
        }
    }
  }
}

// ---------------- K3: reduce partials + LayerNorm + residual + pos ----------------
__global__ __launch_bounds__(128) void k_finish(
    const __hip_bfloat16* __restrict__ hp_part,
    const __hip_bfloat16* __restrict__ ppart, const float* __restrict__ hin,
    const float* __restrict__ pos, const float* __restrict__ gamma,
    const float* __restrict__ beta, float* __restrict__ hout,
    float* __restrict__ out_pos) {
  __shared__ float red[2][2];
  const int i = blockIdx.x, d = threadIdx.x;
  float Li[4];
  float v = 0.f;
#pragma unroll
  for (int hx = 0; hx < 4; ++hx) {
    float L = 0.f, hv = 0.f;
#pragma unroll
    for (int jh = 0; jh < 4; ++jh) {
      L += __bfloat162float(ppart[((size_t)(jh * 4 + hx) * NN + i) * 4 + 3]);
      hv += __bfloat162float(hp_part[((size_t)(jh * 4 + hx) * NN + i) * 128 + d]);
    }
    Li[hx] = 1.f / L;
    v += hv * Li[hx];
  }
  v *= 0.25f;
  float s = v, sq = v * v;
#pragma unroll
  for (int off = 32; off >= 1; off >>= 1) {
    s += __shfl_xor(s, off, 64);
    sq += __shfl_xor(sq, off, 64);
  }
  const int wv = d >> 6;
  if ((d & 63) == 0) { red[wv][0] = s; red[wv][1] = sq; }
  __syncthreads();
  s = red[0][0] + red[1][0];
  sq = red[0][1] + red[1][1];
  const float mu = s * (1.f / 128.f);
  const float var = sq * (1.f / 128.f) - mu * mu;
  const float hn = (v - mu) * rsqrtf(var + 1e-5f) * gamma[d] + beta[d];
  hout[i * 128 + d] = hin[i * 128 + d] + hn;
  if (d < 3) {
    float sp = 0.f;
#pragma unroll
    for (int hx = 0; hx < 4; ++hx) {
      float pv = 0.f;
#pragma unroll
      for (int jh = 0; jh < 4; ++jh)
        pv += __bfloat162float(ppart[((size_t)(jh * 4 + hx) * NN + i) * 4 + d]);
      sp += pv * Li[hx];
    }
    out_pos[i * 3 + d] = 2.f * pos[i * 3 + d] - 0.25f * sp;
  }
}

extern "C" void kernel_launch(void* const* d_in, const int* in_sizes, int n_in,
                              void* d_out, int out_size, void* d_ws, size_t ws_size,
                              hipStream_t stream) {
  const float* h     = (const float*)d_in[0];
  const int*   adj   = (const int*)d_in[1];
  const float* pos   = (const float*)d_in[2];
  const float* W     = (const float*)d_in[3];
  const float* a     = (const float*)d_in[4];
  const float* gamma = (const float*)d_in[5];
  const float* beta  = (const float*)d_in[6];
  float* out = (float*)d_out;

  unsigned char* ws = (unsigned char*)d_ws;
  _Float16* vfrag   = (_Float16*)ws;                         // 4,194,304 B
  _Float16* posfrag = (_Float16*)(ws + 4194304);             // 131,072 B
  float* src        = (float*)(ws + 4194304 + 131072);       // 65,536 B
  float* tgt        = (float*)(ws + 4194304 + 131072 + 65536);
  __hip_bfloat16* hp_part =
      (__hip_bfloat16*)(ws + 4194304 + 131072 + 131072);     // 16,777,216 B
  __hip_bfloat16* ppart =
      (__hip_bfloat16*)(ws + 4194304 + 131072 + 131072 + 16777216);  // 524,288 B

  k_htgemm<<<NN / 16, 512, 0, stream>>>(h, W, a, pos, vfrag, posfrag, src, tgt);
  k_attn<<<(NN / 32) * 4, 512, 0, stream>>>(vfrag, posfrag, adj, pos, src, tgt,
                                            hp_part, ppart);
  k_finish<<<NN, 128, 0, stream>>>(hp_part, ppart, h, pos, gamma, beta, out,
                                   out + NN * 128);
}